// Round 5
// baseline (787.630 us; speedup 1.0000x reference)
//
#include <hip/hip_runtime.h>
#include <hip/hip_bf16.h>

#define BATCH 256
#define FIN 2048
#define D 8192
#define NC 14951

typedef __attribute__((ext_vector_type(8))) short short8;
typedef __attribute__((ext_vector_type(4))) float f32x4;

__device__ __forceinline__ unsigned short f2bf(float f) {
    unsigned u = __float_as_uint(f);
    u += 0x7FFFu + ((u >> 16) & 1u);
    return (unsigned short)(u >> 16);
}
__device__ __forceinline__ float bf2f(unsigned short h) {
    return __uint_as_float(((unsigned)h) << 16);
}

// padded LDS index (float2 units): insert 1 pad per 8 -> breaks pow2 strides
#define PADI(i) ((i) + ((i) >> 3))

__device__ __forceinline__ float2 cmul(float2 a, float2 b) {
    return make_float2(a.x * b.x - a.y * b.y, a.x * b.y + a.y * b.x);
}

// ---------------- kernel 0: out[m][n] = bias[n] (gemm accumulates on top) ---
__global__ __launch_bounds__(1024) void bias_fill_kernel(
    const float* __restrict__ bias, float* __restrict__ out)
{
    const int m = blockIdx.x;
    float* row = out + (size_t)m * NC;
    for (int n = threadIdx.x; n < NC; n += 1024) row[n] = bias[n];
}

// ---------------- kernel 1: sketch + radix-8 FFT + product + IFFT ----------
// (unchanged from round 4 — verified passing; ~30-40 us estimated)
template<int SGN>
__device__ __forceinline__ void radix8_stage(const float2* __restrict__ src,
                                             float2* __restrict__ dst,
                                             int ns, int tid)
{
    float2 z[8];
#pragma unroll
    for (int k = 0; k < 8; ++k) z[k] = src[PADI(tid + k * 1024)];

    const int j = tid & (ns - 1);
    const float ang = (float)SGN * 6.28318530717958647692f * ((float)j / (float)(8 * ns));
    float sn, cs;
    __sincosf(ang, &sn, &cs);
    float2 w1 = make_float2(cs, sn);
    float2 w2 = cmul(w1, w1), w3 = cmul(w2, w1), w4 = cmul(w2, w2);
    float2 w5 = cmul(w4, w1), w6 = cmul(w4, w2), w7 = cmul(w4, w3);

    float2 u0 = z[0],           u1 = cmul(z[1], w1), u2 = cmul(z[2], w2), u3 = cmul(z[3], w3);
    float2 u4 = cmul(z[4], w4), u5 = cmul(z[5], w5), u6 = cmul(z[6], w6), u7 = cmul(z[7], w7);

    const float sg = (float)SGN;
    float2 t0 = make_float2(u0.x + u4.x, u0.y + u4.y);
    float2 t1 = make_float2(u0.x - u4.x, u0.y - u4.y);
    float2 t2 = make_float2(u2.x + u6.x, u2.y + u6.y);
    float2 t3 = make_float2(u2.x - u6.x, u2.y - u6.y);
    float2 E0 = make_float2(t0.x + t2.x, t0.y + t2.y);
    float2 E2 = make_float2(t0.x - t2.x, t0.y - t2.y);
    float2 E1 = make_float2(t1.x - sg * t3.y, t1.y + sg * t3.x);
    float2 E3 = make_float2(t1.x + sg * t3.y, t1.y - sg * t3.x);
    float2 s0 = make_float2(u1.x + u5.x, u1.y + u5.y);
    float2 s1 = make_float2(u1.x - u5.x, u1.y - u5.y);
    float2 s2 = make_float2(u3.x + u7.x, u3.y + u7.y);
    float2 s3 = make_float2(u3.x - u7.x, u3.y - u7.y);
    float2 O0 = make_float2(s0.x + s2.x, s0.y + s2.y);
    float2 O2 = make_float2(s0.x - s2.x, s0.y - s2.y);
    float2 O1 = make_float2(s1.x - sg * s3.y, s1.y + sg * s3.x);
    float2 O3 = make_float2(s1.x + sg * s3.y, s1.y - sg * s3.x);
    const float C8 = 0.70710678118654752440f;
    float2 P1 = make_float2(C8 * (O1.x - sg * O1.y), C8 * (O1.y + sg * O1.x));
    float2 P2 = make_float2(-sg * O2.y, sg * O2.x);
    float2 P3 = make_float2(C8 * (-O3.x - sg * O3.y), C8 * (sg * O3.x - O3.y));

    const int base = 8 * tid - 7 * j;   // = 8*(tid-j) + j
    dst[PADI(base + 0 * ns)] = make_float2(E0.x + O0.x, E0.y + O0.y);
    dst[PADI(base + 1 * ns)] = make_float2(E1.x + P1.x, E1.y + P1.y);
    dst[PADI(base + 2 * ns)] = make_float2(E2.x + P2.x, E2.y + P2.y);
    dst[PADI(base + 3 * ns)] = make_float2(E3.x + P3.x, E3.y + P3.y);
    dst[PADI(base + 4 * ns)] = make_float2(E0.x - O0.x, E0.y - O0.y);
    dst[PADI(base + 5 * ns)] = make_float2(E1.x - P1.x, E1.y - P1.y);
    dst[PADI(base + 6 * ns)] = make_float2(E2.x - P2.x, E2.y - P2.y);
    dst[PADI(base + 7 * ns)] = make_float2(E3.x - P3.x, E3.y - P3.y);
}

template<int SGN>
__device__ __forceinline__ void radix2_final(const float2* __restrict__ src,
                                             float2* __restrict__ dst, int tid)
{
#pragma unroll
    for (int it = 0; it < 4; ++it) {
        int i = tid + it * 1024;
        float2 a = src[PADI(i)];
        float2 c = src[PADI(i + 4096)];
        float ang = (float)SGN * 6.28318530717958647692f * ((float)i * (1.0f / 8192.0f));
        float sn, cs;
        __sincosf(ang, &sn, &cs);
        float2 wc = make_float2(cs * c.x - sn * c.y, cs * c.y + sn * c.x);
        dst[PADI(i)]        = make_float2(a.x + wc.x, a.y + wc.y);
        dst[PADI(i + 4096)] = make_float2(a.x - wc.x, a.y - wc.y);
    }
}

__global__ __launch_bounds__(1024) void cbp_kernel(
    const float* __restrict__ x, const int* __restrict__ h1, const int* __restrict__ h2,
    const float* __restrict__ s1, const float* __restrict__ s2,
    unsigned short* __restrict__ Ah, unsigned short* __restrict__ Al)
{
    __shared__ float2 bufA[9216];   // PADI(8192)
    __shared__ float2 bufB[9216];
    const int b = blockIdx.x;
    const int tid = threadIdx.x;

    for (int i = tid; i < 9216; i += 1024) bufA[i] = make_float2(0.f, 0.f);
    __syncthreads();

    const float* xrow = x + (size_t)b * FIN;
#pragma unroll
    for (int it = 0; it < 2; ++it) {
        int i = tid + it * 1024;
        float v = xrow[i];
        atomicAdd(&bufA[PADI(h1[i])].x, s1[i] * v);
        atomicAdd(&bufA[PADI(h2[i])].y, s2[i] * v);
    }
    __syncthreads();

    radix8_stage<-1>(bufA, bufB, 1, tid);   __syncthreads();
    radix8_stage<-1>(bufB, bufA, 8, tid);   __syncthreads();
    radix8_stage<-1>(bufA, bufB, 64, tid);  __syncthreads();
    radix8_stage<-1>(bufB, bufA, 512, tid); __syncthreads();
    radix2_final<-1>(bufA, bufB, tid);      __syncthreads();

#pragma unroll
    for (int it = 0; it < 8; ++it) {
        int k = tid + it * 1024;
        float2 zk = bufB[PADI(k)];
        float2 zm = bufB[PADI((8192 - k) & 8191)];
        float f1x = 0.5f * (zk.x + zm.x);
        float f1y = 0.5f * (zk.y - zm.y);
        float gx  = 0.5f * (zk.x - zm.x);
        float gy  = 0.5f * (zk.y + zm.y);
        float f2x = gy, f2y = -gx;   // F2 = -i*(gx + i*gy)
        bufA[PADI(k)] = make_float2(f1x * f2x - f1y * f2y, f1x * f2y + f1y * f2x);
    }
    __syncthreads();

    radix8_stage<1>(bufA, bufB, 1, tid);   __syncthreads();
    radix8_stage<1>(bufB, bufA, 8, tid);   __syncthreads();
    radix8_stage<1>(bufA, bufB, 64, tid);  __syncthreads();
    radix8_stage<1>(bufB, bufA, 512, tid); __syncthreads();
    radix2_final<1>(bufA, bufB, tid);      __syncthreads();

    const float invD = 1.0f / 8192.0f;
    unsigned short* ah = Ah + (size_t)b * D;
    unsigned short* al = Al + (size_t)b * D;
#pragma unroll
    for (int it = 0; it < 8; ++it) {
        int t = tid + it * 1024;
        float v = bufB[PADI(t)].x * invD;
        unsigned short h = f2bf(v);
        unsigned short l = f2bf(v - bf2f(h));
        ah[t] = h;
        al[t] = l;
    }
}

// ---------------- kernel 2: GEMM out[m,n] += sum_k cbp[m,k]*W[n,k] ---------
// Grid 468 = 117 n-tiles x 2 m-halves x 2 k-halves. 512 thr / 8 waves.
// Block tile 128x128, wave tile 32x64 (4M x 2N waves), KS=32, k-split x2.
// A(hi,lo bf16) via global_load_lds double-buffered; B = bf16-RTN of W via
// v_cvt_pk, reg->LDS double-buffered. 2-term split: (Ah+Al)*Bh.
// Single raw s_barrier per K-step with COUNTED s_waitcnt vmcnt(4) (T4):
// each iter's 4 loads (2 gload_lds A + 2 W float4) stay in flight across
// the barrier; vmcnt(4) before compute drains exactly the previous iter's 4.
// 64-B LDS rows -> conflict-free reads/writes, no swizzle needed.
#define BMT 128
#define BNT 128
#define KS 32
#define KHALF 4096

#define VMCNT4() asm volatile("s_waitcnt vmcnt(4)" ::: "memory")
#define VMCNT0() asm volatile("s_waitcnt vmcnt(0)" ::: "memory")
#define LGKM0()  asm volatile("s_waitcnt lgkmcnt(0)" ::: "memory")

__global__ __launch_bounds__(512, 4) void gemm_kernel(
    const unsigned short* __restrict__ Ah, const unsigned short* __restrict__ Al,
    const float* __restrict__ W, float* __restrict__ out)
{
    __shared__ __align__(16) unsigned short lA[2][2][BMT * KS];  // 32 KB
    __shared__ __align__(16) unsigned short lB[2][BNT * KS];     // 16 KB

    const int tid = threadIdx.x;
    const int wave = tid >> 6;
    const int lane = tid & 63;
    const int wm = wave >> 1;     // 0..3 -> rows 32*wm
    const int wn = wave & 1;      // 0..1 -> cols 64*wn
    const int r16 = lane & 15;
    const int hi16 = (lane >> 4) * 16;   // byte offset of 16B k-chunk

    // bijective XCD swizzle over 468 blocks (4 XCDs x 59 + 4 x 58 chunks);
    // the 4 blocks of one n-tile (2 mh x 2 kh) stay consecutive -> same XCD.
    const int orig = blockIdx.x;
    const int xcd = orig & 7, idx = orig >> 3;
    const int wg = (xcd < 4 ? xcd * 59 : 236 + (xcd - 4) * 58) + idx;
    const int nt = wg >> 2;
    const int mh = (wg >> 1) & 1;
    const int kh = wg & 1;
    const int n0 = nt * BNT;
    const int m0 = mh * BMT;
    const int kb = kh * KHALF;

    // staging decomposition (both A and B tiles: 128 rows x 32 k)
    const int srow = tid >> 2;          // 0..127
    const int sc   = tid & 3;           // 16B chunk within 64B row

    f32x4 acc[2][4];
#pragma unroll
    for (int i = 0; i < 2; ++i)
#pragma unroll
        for (int j = 0; j < 4; ++j) acc[i][j] = (f32x4){0.f, 0.f, 0.f, 0.f};

    // W source row clamped in-bounds so loads are exec-uniform (vmcnt-uniform);
    // values for n >= NC are garbage but land in discarded acc columns.
    const int nW = (n0 + srow < NC) ? (n0 + srow) : (NC - 1);
    const float* wsrc = W + (size_t)nW * D + kb + sc * 8;

    const unsigned short* asrcH = Ah + (size_t)(m0 + srow) * D + kb + sc * 8;
    const unsigned short* asrcL = Al + (size_t)(m0 + srow) * D + kb + sc * 8;

    float4 wr0a, wr0b, wr1a, wr1b;   // two named W reg sets (ping-pong)

    auto LOADW = [&](int kt, float4& a, float4& b) {
        const float4* gw = reinterpret_cast<const float4*>(wsrc + kt * KS);
        a = gw[0];
        b = gw[1];
    };

    auto STAGE_A = [&](int kt, int buf) {
        char* dstH = (char*)&lA[buf][0][0] + wave * 1024;
        char* dstL = (char*)&lA[buf][1][0] + wave * 1024;
        __builtin_amdgcn_global_load_lds(
            (const __attribute__((address_space(1))) void*)(asrcH + kt * KS),
            (__attribute__((address_space(3))) void*)dstH, 16, 0, 0);
        __builtin_amdgcn_global_load_lds(
            (const __attribute__((address_space(1))) void*)(asrcL + kt * KS),
            (__attribute__((address_space(3))) void*)dstL, 16, 0, 0);
    };

    auto STOREB = [&](const float4& a, const float4& b, int buf) {
        unsigned r0, r1, r2, r3;
        asm("v_cvt_pk_bf16_f32 %0, %1, %2" : "=v"(r0) : "v"(a.x), "v"(a.y));
        asm("v_cvt_pk_bf16_f32 %0, %1, %2" : "=v"(r1) : "v"(a.z), "v"(a.w));
        asm("v_cvt_pk_bf16_f32 %0, %1, %2" : "=v"(r2) : "v"(b.x), "v"(b.y));
        asm("v_cvt_pk_bf16_f32 %0, %1, %2" : "=v"(r3) : "v"(b.z), "v"(b.w));
        uint4 v; v.x = r0; v.y = r1; v.z = r2; v.w = r3;
        *reinterpret_cast<uint4*>((char*)&lB[buf][0] + srow * 64 + sc * 16) = v;
    };

    auto COMPUTE = [&](int buf) {
        short8 a_hi[2], a_lo[2], bf[4];
#pragma unroll
        for (int rb = 0; rb < 2; ++rb) {
            const int bo = (wm * 32 + rb * 16 + r16) * 64 + hi16;
            a_hi[rb] = *reinterpret_cast<const short8*>((const char*)&lA[buf][0][0] + bo);
            a_lo[rb] = *reinterpret_cast<const short8*>((const char*)&lA[buf][1][0] + bo);
        }
#pragma unroll
        for (int nb = 0; nb < 4; ++nb) {
            const int bo = (wn * 64 + nb * 16 + r16) * 64 + hi16;
            bf[nb] = *reinterpret_cast<const short8*>((const char*)&lB[buf][0] + bo);
        }
#pragma unroll
        for (int rb = 0; rb < 2; ++rb)
#pragma unroll
            for (int nb = 0; nb < 4; ++nb) {
                acc[rb][nb] = __builtin_amdgcn_mfma_f32_16x16x32_bf16(a_hi[rb], bf[nb], acc[rb][nb], 0, 0, 0);
                acc[rb][nb] = __builtin_amdgcn_mfma_f32_16x16x32_bf16(a_lo[rb], bf[nb], acc[rb][nb], 0, 0, 0);
            }
    };

    // ---- prologue: B(0) in lB[0], A(0) + W(1) in flight ----
    LOADW(0, wr0a, wr0b);
    STAGE_A(0, 0);
    STOREB(wr0a, wr0b, 0);         // compiler waits W(0)'s vmcnt for the regs
    LOADW(1, wr0a, wr0b);          // ready set for iter 0
    LGKM0();
    __builtin_amdgcn_s_barrier();  // lB[0] visible; A(0)+W(1) still in flight

    // ---- main loop: iters 0..125 (unrolled x2 for W reg ping-pong) ----
#define ITER(K, RDYA, RDYB, FLYA, FLYB)                                    \
    {                                                                      \
        STAGE_A((K) + 1, ((K) + 1) & 1);                                   \
        LOADW((K) + 2, FLYA, FLYB);                                        \
        VMCNT4();                /* A(K) landed; W(K+1) landed */           \
        COMPUTE((K) & 1);                                                  \
        STOREB(RDYA, RDYB, ((K) + 1) & 1);                                 \
        LGKM0();                                                           \
        __builtin_amdgcn_s_barrier();                                      \
    }

    for (int kp = 0; kp < 63; ++kp) {
        const int k = kp * 2;
        ITER(k,     wr0a, wr0b, wr1a, wr1b);
        ITER(k + 1, wr1a, wr1b, wr0a, wr0b);
    }

    // ---- tail iter 126 (no LOADW; ready = wr0 = W(127)) ----
    STAGE_A(127, 1);
    VMCNT4();                       // drains A(126); leaves W(127)+A(127)
    COMPUTE(0);
    STOREB(wr0a, wr0b, 1);
    LGKM0();
    __builtin_amdgcn_s_barrier();

    // ---- tail iter 127 ----
    VMCNT0();                       // A(127) landed
    COMPUTE(1);

    // ---- epilogue: atomic accumulate (bias pre-filled by bias_fill) ----
    const int rq = (lane >> 4) * 4;
#pragma unroll
    for (int nb = 0; nb < 4; ++nb) {
        const int nc = n0 + wn * 64 + nb * 16 + r16;
        if (nc < NC) {
#pragma unroll
            for (int rb = 0; rb < 2; ++rb)
#pragma unroll
                for (int r = 0; r < 4; ++r) {
                    const int m = m0 + wm * 32 + rb * 16 + rq + r;
                    atomicAdd(&out[(size_t)m * NC + nc], acc[rb][nb][r]);
                }
        }
    }
}

extern "C" void kernel_launch(void* const* d_in, const int* in_sizes, int n_in,
                              void* d_out, int out_size, void* d_ws, size_t ws_size,
                              hipStream_t stream) {
    (void)in_sizes; (void)n_in; (void)out_size;
    const float* x  = (const float*)d_in[0];
    const int*   h1 = (const int*)d_in[1];
    const int*   h2 = (const int*)d_in[2];
    const float* s1 = (const float*)d_in[3];
    const float* s2 = (const float*)d_in[4];
    const float* W  = (const float*)d_in[5];
    const float* bias = (const float*)d_in[6];
    float* out = (float*)d_out;

    const size_t A_BYTES = (size_t)BATCH * D * sizeof(unsigned short);  // 4 MB
    if (ws_size < 2 * A_BYTES) return;

    unsigned short* Ahp = (unsigned short*)d_ws;
    unsigned short* Alp = (unsigned short*)((char*)d_ws + A_BYTES);

    bias_fill_kernel<<<dim3(BATCH), dim3(1024), 0, stream>>>(bias, out);
    cbp_kernel<<<dim3(BATCH), dim3(1024), 0, stream>>>(x, h1, h2, s1, s2, Ahp, Alp);
    // 117 n-tiles x 2 m-halves x 2 k-halves = 468 blocks
    gemm_kernel<<<dim3(468), dim3(512), 0, stream>>>(Ahp, Alp, W, out);
}